// Round 8
// baseline (210.210 us; speedup 1.0000x reference)
//
#include <hip/hip_runtime.h>

// Problem constants (from reference setup_inputs)
#define N_PRE_C   50000
#define N_TYPES_C 20
#define N_BASIS_C 5
#define NB        2                    // batches
#define WORDS32   1568                 // ceil(50000/32)=1563, padded to 1568 (wave-aligned)

typedef unsigned long long ull;
typedef unsigned int uint_t;
// clang ext_vector types: __builtin_nontemporal_load needs these (HIP_vector_type invalid)
typedef int   __attribute__((ext_vector_type(4))) i4v;
typedef float __attribute__((ext_vector_type(4))) f4v;

// ---------------------------------------------------------------------------
// Kernel 1: pack rec_z_buf (B x N_PRE floats, binary) into a 32-bit bitmask.
// Layout: mask32[word32][b] so one 8B uint2 read covers both batches.
// Also zeroes out_t (grid-stride float4): no separate memset dispatch.
// ---------------------------------------------------------------------------
__global__ __launch_bounds__(256) void pack_spikes(const float* __restrict__ rec_z,
                                                   uint_t* __restrict__ mask32,
                                                   float4* __restrict__ zbuf,
                                                   int zquads) {
    const int b = blockIdx.y;
    const int i = blockIdx.x * 256 + threadIdx.x;   // [0, WORDS32*32)
    float v = 0.f;
    if (i < N_PRE_C) v = rec_z[b * N_PRE_C + i];
    const ull m = __ballot(v > 0.f);
    if ((threadIdx.x & 63) == 0) {                  // i is a multiple of 64
        const int w32 = i >> 5;                     // even
        mask32[(w32 + 0) * NB + b] = (uint_t)(m & 0xffffffffull);
        mask32[(w32 + 1) * NB + b] = (uint_t)(m >> 32);
    }
    if (zbuf != nullptr) {
        const int nt = gridDim.x * gridDim.y * 256;
        int q = (blockIdx.y * gridDim.x + blockIdx.x) * 256 + threadIdx.x;
        const float4 z = make_float4(0.f, 0.f, 0.f, 0.f);
        for (; q < zquads; q += nt) zbuf[q] = z;
    }
}

// ---------------------------------------------------------------------------
// Kernel 2: R6 structure (no LDS, no barrier, 8 syn/thread, 8 independent
// up-front loads, 8 independent mask gathers, fire-and-forget atomics) with
// ONE change: the streaming arrays (idx/w/sid) are loaded NON-TEMPORAL
// (nt-flagged global_load_dwordx4, evict-first).
// Theory: the 160 MB stream thrashes the 32KB L1 (625 KB/CU flows through),
// evicting the 12.5KB mask, so every gather escalates to L2 (~200cy) and
// saturates the CU's outstanding-miss capacity. nt stream loads keep the
// mask L1-resident; gathers become L1 hits.
// ---------------------------------------------------------------------------
__global__ __launch_bounds__(256) void syn_scatter_t(
    const int*   __restrict__ idxp,    // [n_syn][2] = (post,pre)
    const float* __restrict__ wp,
    const int*   __restrict__ sidp,
    const uint2* __restrict__ mask2,   // [WORDS32] {b0,b1}, read via L1 (temporal)
    float* __restrict__ out_t,         // [NB*n_post][N_TYPES] accumulator (zeroed)
    int n_post, int n_syn) {
    const int t = blockIdx.x * 256 + threadIdx.x;
    const long base = (long)t * 8;
    if (base >= n_syn) return;
    const int np20 = n_post * N_TYPES_C;

    if (base + 8 <= n_syn) {
        // ---- stage 1: 8 independent coalesced 16B NON-TEMPORAL loads ----
        const i4v* ip = (const i4v*)idxp;
        const f4v* fp = (const f4v*)wp;
        const i4v* sp = (const i4v*)sidp;
        const i4v pA = __builtin_nontemporal_load(&ip[(long)t * 4 + 0]);
        const i4v pB = __builtin_nontemporal_load(&ip[(long)t * 4 + 1]);
        const i4v pC = __builtin_nontemporal_load(&ip[(long)t * 4 + 2]);
        const i4v pD = __builtin_nontemporal_load(&ip[(long)t * 4 + 3]);
        const f4v wA = __builtin_nontemporal_load(&fp[(long)t * 2 + 0]);
        const f4v wB = __builtin_nontemporal_load(&fp[(long)t * 2 + 1]);
        const i4v sA = __builtin_nontemporal_load(&sp[(long)t * 2 + 0]);
        const i4v sB = __builtin_nontemporal_load(&sp[(long)t * 2 + 1]);
        // ---- stage 2: 8 independent 8B gathers from L1-resident mask ----
        const uint2 m0 = mask2[pA.y >> 5];
        const uint2 m1 = mask2[pA.w >> 5];
        const uint2 m2 = mask2[pB.y >> 5];
        const uint2 m3 = mask2[pB.w >> 5];
        const uint2 m4 = mask2[pC.y >> 5];
        const uint2 m5 = mask2[pC.w >> 5];
        const uint2 m6 = mask2[pD.y >> 5];
        const uint2 m7 = mask2[pD.w >> 5];
        // ---- stage 3: bit tests + fire-and-forget atomics ----
        #define ONE(POST, PRE, MW, WV, TT)                                    \
            {                                                                 \
                const uint_t bit = 1u << ((PRE) & 31);                        \
                if ((((MW).x | (MW).y) & bit) != 0u) {                        \
                    const int o = (POST) * N_TYPES_C + (TT);                  \
                    if ((MW).x & bit) unsafeAtomicAdd(out_t + o, (WV));       \
                    if ((MW).y & bit) unsafeAtomicAdd(out_t + o + np20, (WV));\
                }                                                             \
            }
        ONE(pA.x, pA.y, m0, wA.x, sA.x)
        ONE(pA.z, pA.w, m1, wA.y, sA.y)
        ONE(pB.x, pB.y, m2, wA.z, sA.z)
        ONE(pB.z, pB.w, m3, wA.w, sA.w)
        ONE(pC.x, pC.y, m4, wB.x, sB.x)
        ONE(pC.z, pC.w, m5, wB.y, sB.y)
        ONE(pD.x, pD.y, m6, wB.z, sB.z)
        ONE(pD.z, pD.w, m7, wB.w, sB.w)
        #undef ONE
    } else {
        for (long s = base; s < n_syn; ++s) {
            const int post = idxp[2 * s], pre = idxp[2 * s + 1];
            const uint2 mw = mask2[pre >> 5];
            const uint_t bit = 1u << (pre & 31);
            if (((mw.x | mw.y) & bit) == 0u) continue;
            const int o = post * N_TYPES_C + sidp[s];
            if (mw.x & bit) unsafeAtomicAdd(out_t + o, wp[s]);
            if (mw.y & bit) unsafeAtomicAdd(out_t + o + np20, wp[s]);
        }
    }
}

// ---------------------------------------------------------------------------
// Kernel 3: combine out_t [rows][20] x basis [20][5] -> out [rows][5].
// ---------------------------------------------------------------------------
__global__ __launch_bounds__(256) void combine_basis(
    const float* __restrict__ out_t,
    const float* __restrict__ basis,   // [N_TYPES][N_BASIS]
    float* __restrict__ out, int rows) {
    __shared__ float sb[N_TYPES_C * N_BASIS_C];
    if (threadIdx.x < N_TYPES_C * N_BASIS_C) sb[threadIdx.x] = basis[threadIdx.x];
    __syncthreads();

    const int r = blockIdx.x * 256 + threadIdx.x;
    if (r >= rows) return;
    const float4* p = (const float4*)(out_t + (long)r * N_TYPES_C);
    float4 v0 = p[0], v1 = p[1], v2 = p[2], v3 = p[3], v4 = p[4];
    float vt[N_TYPES_C] = {v0.x, v0.y, v0.z, v0.w, v1.x, v1.y, v1.z, v1.w,
                           v2.x, v2.y, v2.z, v2.w, v3.x, v3.y, v3.z, v3.w,
                           v4.x, v4.y, v4.z, v4.w};
    float acc[N_BASIS_C] = {0.f, 0.f, 0.f, 0.f, 0.f};
    #pragma unroll
    for (int t = 0; t < N_TYPES_C; ++t) {
        #pragma unroll
        for (int k = 0; k < N_BASIS_C; ++k)
            acc[k] += vt[t] * sb[t * N_BASIS_C + k];   // sb read is a broadcast
    }
    float* o = out + (long)r * N_BASIS_C;
    #pragma unroll
    for (int k = 0; k < N_BASIS_C; ++k) o[k] = acc[k];
}

// ---------------------------------------------------------------------------
// Fallback (only if ws too small): direct 5-atomic scatter into out.
// ---------------------------------------------------------------------------
__global__ __launch_bounds__(256) void syn_scatter_direct(
    const int4* __restrict__ idx2, const float4* __restrict__ w4,
    const int4* __restrict__ sid4, const float* __restrict__ basis,
    const uint2* __restrict__ mask2, float* __restrict__ out,
    int n_post, int n_syn) {
    __shared__ float sb[N_TYPES_C][N_BASIS_C];
    for (int t = threadIdx.x; t < N_TYPES_C * N_BASIS_C; t += 256)
        ((float*)sb)[t] = basis[t];
    __syncthreads();
    const int t = blockIdx.x * 256 + threadIdx.x;
    const long base = (long)t * 4;
    if (base >= n_syn) return;

    auto apply = [&](int post, int pre, float wv, int tt) {
        const uint2 mw = mask2[pre >> 5];
        const uint_t bit = 1u << (pre & 31);
        if (((mw.x | mw.y) & bit) == 0u) return;
        const float* bs = sb[tt];
        float c[N_BASIS_C];
        #pragma unroll
        for (int k = 0; k < N_BASIS_C; ++k) c[k] = wv * bs[k];
        if (mw.x & bit) {
            float* o = out + (long)post * N_BASIS_C;
            #pragma unroll
            for (int k = 0; k < N_BASIS_C; ++k) unsafeAtomicAdd(o + k, c[k]);
        }
        if (mw.y & bit) {
            float* o = out + (long)(n_post + post) * N_BASIS_C;
            #pragma unroll
            for (int k = 0; k < N_BASIS_C; ++k) unsafeAtomicAdd(o + k, c[k]);
        }
    };

    if (base + 4 <= n_syn) {
        const int4   p01 = idx2[t * 2];
        const int4   p23 = idx2[t * 2 + 1];
        const float4 wv  = w4[t];
        const int4   sv  = sid4[t];
        apply(p01.x, p01.y, wv.x, sv.x);
        apply(p01.z, p01.w, wv.y, sv.y);
        apply(p23.x, p23.y, wv.z, sv.z);
        apply(p23.z, p23.w, wv.w, sv.w);
    } else {
        const int*   idx = (const int*)idx2;
        const float* w   = (const float*)w4;
        const int*   sid = (const int*)sid4;
        for (long s = base; s < n_syn; ++s)
            apply(idx[2 * s], idx[2 * s + 1], w[s], sid[s]);
    }
}

extern "C" void kernel_launch(void* const* d_in, const int* in_sizes, int n_in,
                              void* d_out, int out_size, void* d_ws, size_t ws_size,
                              hipStream_t stream) {
    const float* rec_z   = (const float*)d_in[0];
    const float* weights = (const float*)d_in[1];
    const float* basis   = (const float*)d_in[2];
    const int*   synidx  = (const int*)d_in[3];
    const int*   synids  = (const int*)d_in[4];
    float*       out     = (float*)d_out;

    const int n_syn  = in_sizes[4];
    const int rows   = out_size / N_BASIS_C;       // NB * n_post
    const int n_post = rows / NB;

    // Workspace layout: out_t [rows][N_TYPES] floats, then mask32.
    const size_t out_t_bytes = (size_t)rows * N_TYPES_C * sizeof(float);  // mult of 16
    const size_t mask_bytes  = (size_t)WORDS32 * NB * sizeof(uint_t);

    if (ws_size >= out_t_bytes + mask_bytes) {
        float*  out_t  = (float*)d_ws;
        uint_t* mask32 = (uint_t*)((char*)d_ws + out_t_bytes);

        const int zquads = (int)(out_t_bytes / sizeof(float4));
        pack_spikes<<<dim3(WORDS32 * 32 / 256, NB), 256, 0, stream>>>(
            rec_z, mask32, (float4*)out_t, zquads);

        const int n_thr  = (n_syn + 7) / 8;        // 8 synapses per thread
        const int blocks = (n_thr + 255) / 256;
        syn_scatter_t<<<blocks, 256, 0, stream>>>(
            synidx, weights, synids,
            (const uint2*)mask32, out_t, n_post, n_syn);

        combine_basis<<<(rows + 255) / 256, 256, 0, stream>>>(out_t, basis, out, rows);
    } else {
        // Fallback: direct 5-atomic scatter (tiny ws).
        uint_t* mask32 = (uint_t*)d_ws;
        (void)hipMemsetAsync(d_out, 0, (size_t)out_size * sizeof(float), stream);
        pack_spikes<<<dim3(WORDS32 * 32 / 256, NB), 256, 0, stream>>>(
            rec_z, mask32, nullptr, 0);
        const int blocks = ((n_syn + 3) / 4 + 255) / 256;
        syn_scatter_direct<<<blocks, 256, 0, stream>>>(
            (const int4*)synidx, (const float4*)weights, (const int4*)synids,
            basis, (const uint2*)mask32, out, n_post, n_syn);
    }
}